// Round 10
// baseline (237.379 us; speedup 1.0000x reference)
//
#include <hip/hip_runtime.h>
#include <math.h>

#define NROWS 8192
#define DIM   128            // row length (fp32 in, bf16 staged)
#define NT    64             // 8192 / 128 tiles per side
#define TRI   2080           // NT*(NT+1)/2 upper-tri tiles incl diag
#define CHUNK 8              // tiles per persistent block
#define NBLK  520            // 2*TRI / CHUNK = 4160/8

typedef __attribute__((ext_vector_type(8))) __bf16 bf16x8;
typedef __attribute__((ext_vector_type(4))) float  f32x4;
typedef __attribute__((ext_vector_type(2))) float  f32x2;

__device__ __forceinline__ unsigned short f2bf(float f) {
    unsigned int u = __float_as_uint(f);
    u += 0x7fffu + ((u >> 16) & 1u);   // round-to-nearest-even
    return (unsigned short)(u >> 16);
}

__device__ __forceinline__ void decode_tile(int t, int& mat, int& ti, int& tj) {
    mat = 0;
    if (t >= TRI) { mat = 1; t -= TRI; }
    int i = 0;
    while (t >= NT - i) { t -= NT - i; ++i; }
    ti = i; tj = i + t;
}

// One wave per row: normalize q-row and k-row, write bf16, per-block align partial.
__global__ __launch_bounds__(256) void norm_kernel(
        const float* __restrict__ q, const float* __restrict__ k,
        unsigned int* __restrict__ qn, unsigned int* __restrict__ kn,
        float* __restrict__ align_part) {
    int wave = threadIdx.x >> 6;
    int lane = threadIdx.x & 63;
    int row  = blockIdx.x * 4 + wave;      // grid = 2048 blocks * 4 waves

    const float2 qv = reinterpret_cast<const float2*>(q)[row * 64 + lane];
    const float2 kv = reinterpret_cast<const float2*>(k)[row * 64 + lane];

    float sq = qv.x * qv.x + qv.y * qv.y;
    float sk = kv.x * kv.x + kv.y * kv.y;
    #pragma unroll
    for (int off = 32; off; off >>= 1) {
        sq += __shfl_xor(sq, off);
        sk += __shfl_xor(sk, off);
    }
    float qi = 1.0f / fmaxf(sqrtf(sq), 1e-12f);
    float ki = 1.0f / fmaxf(sqrtf(sk), 1e-12f);
    float qx = qv.x * qi, qy = qv.y * qi;
    float kx = kv.x * ki, ky = kv.y * ki;

    qn[row * 64 + lane] = (unsigned int)f2bf(qx) | ((unsigned int)f2bf(qy) << 16);
    kn[row * 64 + lane] = (unsigned int)f2bf(kx) | ((unsigned int)f2bf(ky) << 16);

    float dx = qx - kx, dy = qy - ky;
    float d2 = dx * dx + dy * dy;
    #pragma unroll
    for (int off = 32; off; off >>= 1) d2 += __shfl_xor(d2, off);

    __shared__ float red[4];
    if (lane == 0) red[wave] = d2;
    __syncthreads();
    if (threadIdx.x == 0)
        align_part[blockIdx.x] = red[0] + red[1] + red[2] + red[3];
}

// Persistent gram: each block walks CHUNK consecutive 128x128 upper-tri tiles.
// Per tile: regs->LDS commit (XOR-swizzled write), barrier, issue NEXT tile's
// global loads (T14 issue-early/write-late), 4 waves (2x2, 64x64 each,
// c[4][4]), Schraudolph packed epilogue accumulated per-thread across tiles.
// __launch_bounds__(256, 2): 2 waves/EU -> 256-VGPR budget, keeps pre[16]
// in registers (R8's default heuristic targeted 4 waves/EU and spilled
// pre[] to scratch: 260 MB/dispatch of scratch writes, 4x slowdown).
__global__ __launch_bounds__(256, 2) void gram_kernel(
        const uint4* __restrict__ qn, const uint4* __restrict__ kn,
        float* __restrict__ unif_q, float* __restrict__ unif_k) {
    __shared__ uint4 lds[4096];            // A: [0,2048) B: [2048,4096), 64 KiB
    __shared__ float redq[4], redk[4];

    int tid = threadIdx.x;
    int wid = tid >> 6, lane = tid & 63;
    int wr = wid >> 1, wc = wid & 1;       // 2x2 wave grid, each 64x64
    int lr = lane & 15, lg = lane >> 4;    // frag row / k-group

    // Schraudolph: e = exp2(K*(g-1)); K1 = 4*log2e*2^23, B = (127-0.05744)*2^23
    const float K1 = 4.0f * 1.4426950408889634f * 8388608.0f;
    const float B  = 1065353216.0f - 0.05744f * 8388608.0f;
    const float K0 = B - K1;

    int t0 = blockIdx.x * CHUNK;

    // ---- prologue: prefetch tile t0 panels into registers (coalesced) ----
    uint4 pre[16];
    int nmat, nti, ntj;
    decode_tile(t0, nmat, nti, ntj);
    {
        const uint4* __restrict__ x = nmat ? kn : qn;
        #pragma unroll
        for (int i = 0; i < 16; ++i) {
            int li = i * 256 + tid;        // 0..4095 over block
            int rr = li >> 4, s = li & 15; // combined row 0..255, slot 0..15
            int r7 = rr & 127;
            int tl = (rr < 128) ? nti : ntj;
            pre[i] = x[((size_t)tl * 128 + r7) * 16 + s];
        }
    }

    f32x2 aq2 = (f32x2){0.f, 0.f}, ak2 = (f32x2){0.f, 0.f};

    for (int u = 0; u < CHUNK; ++u) {
        // ---- commit prefetched panels to LDS, XOR-swizzled write ----
        #pragma unroll
        for (int i = 0; i < 16; ++i) {
            int li = i * 256 + tid;
            int rr = li >> 4, s = li & 15;
            lds[rr * 16 + (s ^ (rr & 15))] = pre[i];
        }
        __syncthreads();

        int dmat = nmat, dti = nti, dtj = ntj;   // tile being computed

        // ---- issue next tile's loads now; completion hides under compute ----
        if (u + 1 < CHUNK) {
            decode_tile(t0 + u + 1, nmat, nti, ntj);
            const uint4* __restrict__ x = nmat ? kn : qn;
            #pragma unroll
            for (int i = 0; i < 16; ++i) {
                int li = i * 256 + tid;
                int rr = li >> 4, s = li & 15;
                int r7 = rr & 127;
                int tl = (rr < 128) ? nti : ntj;
                pre[i] = x[((size_t)tl * 128 + r7) * 16 + s];
            }
        }

        // ---- MFMA: 64x64 per wave, K = 128 = 4*32 ----
        f32x4 c[4][4];
        #pragma unroll
        for (int m = 0; m < 4; ++m)
            #pragma unroll
            for (int n = 0; n < 4; ++n)
                c[m][n] = (f32x4){0.f, 0.f, 0.f, 0.f};

        #pragma unroll
        for (int ks = 0; ks < 4; ++ks) {
            int slot = ks * 4 + lg;
            bf16x8 a[4], b[4];
            #pragma unroll
            for (int m = 0; m < 4; ++m) {
                int r = wr * 64 + m * 16 + lr;
                a[m] = *reinterpret_cast<const bf16x8*>(&lds[r * 16 + (slot ^ (r & 15))]);
            }
            #pragma unroll
            for (int n = 0; n < 4; ++n) {
                int r = wc * 64 + n * 16 + lr;
                b[n] = *reinterpret_cast<const bf16x8*>(&lds[2048 + r * 16 + (slot ^ (r & 15))]);
            }
            #pragma unroll
            for (int m = 0; m < 4; ++m)
                #pragma unroll
                for (int n = 0; n < 4; ++n)
                    c[m][n] = __builtin_amdgcn_mfma_f32_16x16x32_bf16(a[m], b[n], c[m][n], 0, 0, 0);
        }

        // ---- epilogue: accumulate exp into per-thread running sums ----
        f32x2 p2 = (f32x2){0.f, 0.f};
        if (dti != dtj) {
            #pragma unroll
            for (int m = 0; m < 4; ++m)
                #pragma unroll
                for (int n = 0; n < 4; ++n) {
                    f32x4 g = c[m][n];
                    f32x2 u0 = (f32x2){g[0], g[1]} * K1 + K0;   // v_pk_fma_f32
                    f32x2 u1 = (f32x2){g[2], g[3]} * K1 + K0;
                    p2 += (f32x2){__int_as_float((int)u0.x),
                                  __int_as_float((int)u0.y)};
                    p2 += (f32x2){__int_as_float((int)u1.x),
                                  __int_as_float((int)u1.y)};
                }
        } else {
            // diagonal tile: strict upper only; clamp at w=0 (g_ii ~ 1)
            int crow0 = wr * 64 + lg * 4;  // C layout: row=(lane>>4)*4+reg
            int ccol0 = wc * 64 + lr;      //           col=lane&15
            float ps = 0.0f;
            #pragma unroll
            for (int m = 0; m < 4; ++m)
                #pragma unroll
                for (int n = 0; n < 4; ++n)
                    #pragma unroll
                    for (int r = 0; r < 4; ++r) {
                        float uu = fminf(fmaf(c[m][n][r], K1, K0), B);
                        float e = __int_as_float((int)uu);
                        int lrow = crow0 + m * 16 + r;
                        int lcol = ccol0 + n * 16;
                        ps += (lcol > lrow) ? e : 0.0f;
                    }
            p2.x = ps;
        }
        if (dmat) ak2 += p2; else aq2 += p2;

        __syncthreads();                   // LDS safe to overwrite next iter
    }

    // ---- one reduce per block ----
    float pq = aq2.x + aq2.y, pk = ak2.x + ak2.y;
    #pragma unroll
    for (int off = 32; off; off >>= 1) {
        pq += __shfl_xor(pq, off);
        pk += __shfl_xor(pk, off);
    }
    if (lane == 0) { redq[wid] = pq; redk[wid] = pk; }
    __syncthreads();
    if (tid == 0) {
        unif_q[blockIdx.x] = redq[0] + redq[1] + redq[2] + redq[3];
        unif_k[blockIdx.x] = redk[0] + redk[1] + redk[2] + redk[3];
    }
}

// Single block: sum all partials in double, emit final scalar.
__global__ __launch_bounds__(256) void finalize(
        const float* __restrict__ align_part,   // [2048]
        const float* __restrict__ unif_q,       // [NBLK]
        const float* __restrict__ unif_k,       // [NBLK]
        float* __restrict__ out) {
    int tid = threadIdx.x;
    double a = 0.0, qs = 0.0, ks = 0.0;
    for (int i = tid; i < 2048; i += 256) a  += (double)align_part[i];
    for (int i = tid; i < NBLK; i += 256) qs += (double)unif_q[i];
    for (int i = tid; i < NBLK; i += 256) ks += (double)unif_k[i];

    __shared__ double sa[256], sq[256], sk[256];
    sa[tid] = a; sq[tid] = qs; sk[tid] = ks;
    __syncthreads();
    for (int s = 128; s; s >>= 1) {
        if (tid < s) {
            sa[tid] += sa[tid + s];
            sq[tid] += sq[tid + s];
            sk[tid] += sk[tid + s];
        }
        __syncthreads();
    }
    if (tid == 0) {
        const double npairs = (double)NROWS * (NROWS - 1) / 2.0;
        double align = sa[0] / (double)NROWS;
        double lq = log(sq[0] / npairs);
        double lk = log(sk[0] / npairs);
        out[0] = (float)(align + 0.5 * (lq + lk));   // LAMDA = 1
    }
}

extern "C" void kernel_launch(void* const* d_in, const int* in_sizes, int n_in,
                              void* d_out, int out_size, void* d_ws, size_t ws_size,
                              hipStream_t stream) {
    const float* q = (const float*)d_in[0];
    const float* k = (const float*)d_in[1];
    char* ws = (char*)d_ws;
    unsigned int* qn = (unsigned int*)ws;                          // 2 MiB bf16
    unsigned int* kn = (unsigned int*)(ws + (size_t)2 * 1024 * 1024);
    float* align_part = (float*)(ws + (size_t)4 * 1024 * 1024);            // 2048 f32
    float* unif_q = (float*)(ws + (size_t)4 * 1024 * 1024 + 16384);        // NBLK f32
    float* unif_k = (float*)(ws + (size_t)4 * 1024 * 1024 + 32768);        // NBLK f32
    float* out = (float*)d_out;

    norm_kernel<<<NROWS / 4, 256, 0, stream>>>(q, k, qn, kn, align_part);
    gram_kernel<<<NBLK, 256, 0, stream>>>((const uint4*)qn, (const uint4*)kn, unif_q, unif_k);
    finalize<<<1, 256, 0, stream>>>(align_part, unif_q, unif_k, out);
}

// Round 12
// 97.505 us; speedup vs baseline: 2.4345x; 2.4345x over previous
//
#include <hip/hip_runtime.h>
#include <math.h>

#define NROWS 8192
#define NT    64             // 8192 / 128 tiles per side
#define TRI   2080           // NT*(NT+1)/2 upper-tri tiles incl diag
#define NTILE (2*TRI)        // 4160 tiles total (q + k)
#define GRID  256            // persistent: 1 block per CU

typedef __attribute__((ext_vector_type(8))) __bf16 bf16x8;
typedef __attribute__((ext_vector_type(4))) float  f32x4;
typedef __attribute__((ext_vector_type(2))) float  f32x2;

__device__ __forceinline__ unsigned short f2bf(float f) {
    unsigned int u = __float_as_uint(f);
    u += 0x7fffu + ((u >> 16) & 1u);   // round-to-nearest-even
    return (unsigned short)(u >> 16);
}

// async global -> LDS, 16B per lane (dest = wave-uniform base + lane*16)
__device__ __forceinline__ void gload_lds16(const uint4* g, uint4* l) {
    __builtin_amdgcn_global_load_lds(
        (const __attribute__((address_space(1))) uint32_t*)
            (const __attribute__((address_space(1))) void*)g,
        (__attribute__((address_space(3))) uint32_t*)
            (__attribute__((address_space(3))) void*)l,
        16, 0, 0);
}

// closed-form triangular decode (disc = (129-2i)^2 is a perfect square,
// fp32-exact) + integer fixup
__device__ __forceinline__ void decode_tile(int t, int& mat, int& ti, int& tj) {
    mat = 0;
    if (t >= TRI) { mat = 1; t -= TRI; }
    float disc = (2.0f * NT + 1.0f) * (2.0f * NT + 1.0f) - 8.0f * (float)t;
    int i = (int)(((2.0f * NT + 1.0f) - sqrtf(disc)) * 0.5f);
    if (i < 0) i = 0;
    if (i > NT - 1) i = NT - 1;
    #pragma unroll
    for (int f = 0; f < 2; ++f) {
        if (i > 0 && (i * NT - i * (i - 1) / 2) > t) --i;
        if (((i + 1) * NT - (i + 1) * i / 2) <= t) ++i;
    }
    ti = i;
    tj = i + (t - (i * NT - i * (i - 1) / 2));
}

// One wave per row: normalize q-row and k-row, write bf16, per-block align partial.
__global__ __launch_bounds__(256) void norm_kernel(
        const float* __restrict__ q, const float* __restrict__ k,
        unsigned int* __restrict__ qn, unsigned int* __restrict__ kn,
        float* __restrict__ align_part) {
    int wave = threadIdx.x >> 6;
    int lane = threadIdx.x & 63;
    int row  = blockIdx.x * 4 + wave;      // grid = 2048 blocks * 4 waves

    const float2 qv = reinterpret_cast<const float2*>(q)[row * 64 + lane];
    const float2 kv = reinterpret_cast<const float2*>(k)[row * 64 + lane];

    float sq = qv.x * qv.x + qv.y * qv.y;
    float sk = kv.x * kv.x + kv.y * kv.y;
    #pragma unroll
    for (int off = 32; off; off >>= 1) {
        sq += __shfl_xor(sq, off);
        sk += __shfl_xor(sk, off);
    }
    float qi = 1.0f / fmaxf(sqrtf(sq), 1e-12f);
    float ki = 1.0f / fmaxf(sqrtf(sk), 1e-12f);
    float qx = qv.x * qi, qy = qv.y * qi;
    float kx = kv.x * ki, ky = kv.y * ki;

    qn[row * 64 + lane] = (unsigned int)f2bf(qx) | ((unsigned int)f2bf(qy) << 16);
    kn[row * 64 + lane] = (unsigned int)f2bf(kx) | ((unsigned int)f2bf(ky) << 16);

    float dx = qx - kx, dy = qy - ky;
    float d2 = dx * dx + dy * dy;
    #pragma unroll
    for (int off = 32; off; off >>= 1) d2 += __shfl_xor(d2, off);

    __shared__ float red[4];
    if (lane == 0) red[wave] = d2;
    __syncthreads();
    if (threadIdx.x == 0)
        align_part[blockIdx.x] = red[0] + red[1] + red[2] + red[3];
}

// Persistent gram, double-buffered LDS, global_load_lds prefetch (zero staging
// VGPRs -> spill-impossible; R8/R10's reg-prefetch spilled 260 MB to scratch).
// 256 blocks x 512 thr (8 waves, 2x4 grid, 64x32 per wave). Per tile: issue
// next tile's async loads into buf^1, compute buf[cur] (hides ~300cy latency),
// one __syncthreads() (vmcnt drain ~0 since loads aged through compute).
// LDS: 2 x 64 KiB -> 1 block/CU, 2 waves/SIMD.
__global__ __launch_bounds__(512) void gram_kernel(
        const uint4* __restrict__ qn, const uint4* __restrict__ kn,
        float* __restrict__ unif_q, float* __restrict__ unif_k) {
    __shared__ uint4 lds[2][4096];         // per buf: A [0,2048) B [2048,4096)
    __shared__ float redq[8], redk[8];

    int tid = threadIdx.x;
    int wid = tid >> 6, lane = tid & 63;
    int wr = wid >> 2, wc = wid & 3;       // 2x4 wave grid, each 64x32
    int lr = lane & 15, lg = lane >> 4;    // frag row / k-group

    // Schraudolph: e = exp2(K*(g-1)); K1 = 4*log2e*2^23, B = (127-0.05744)*2^23
    const float K1 = 4.0f * 1.4426950408889634f * 8388608.0f;
    const float B  = 1065353216.0f - 0.05744f * 8388608.0f;
    const float K0 = B - K1;

    // stage tile (mat,ti,tj) into buf: 64 gload_lds insts, linear LDS dest,
    // inverse-XOR'd global source (involution; read applies same XOR)
    auto stage = [&](uint4* buf, int mat, int ti, int tj) {
        const uint4* __restrict__ x = mat ? kn : qn;
        #pragma unroll
        for (int it = 0; it < 8; ++it) {
            int inst = wid * 8 + it;       // 0..63, uniform per wave
            int li   = inst * 64 + lane;   // element 0..4095
            int rr   = li >> 4, s = li & 15;
            int tile = (rr < 128) ? ti : tj;
            int r7   = rr & 127;
            int ss   = s ^ (rr & 15);
            gload_lds16(&x[((size_t)tile * 128 + r7) * 16 + ss], &buf[inst * 64]);
        }
    };

    f32x2 aq2 = (f32x2){0.f, 0.f}, ak2 = (f32x2){0.f, 0.f};

    int t = blockIdx.x;
    int cmat, cti, ctj;
    decode_tile(t, cmat, cti, ctj);
    stage(lds[0], cmat, cti, ctj);
    __syncthreads();                       // prologue drain (once)
    int cur = 0;

    while (t < NTILE) {
        int tn = t + GRID;
        int nmat = 0, nti = 0, ntj = 0;
        if (tn < NTILE) {                  // issue next tile's loads NOW
            decode_tile(tn, nmat, nti, ntj);
            stage(lds[cur ^ 1], nmat, nti, ntj);
        }

        // ---- compute current tile from lds[cur] ----
        const uint4* bufA = &lds[cur][0];
        const uint4* bufB = &lds[cur][2048];

        f32x4 c[4][2];
        #pragma unroll
        for (int m = 0; m < 4; ++m)
            #pragma unroll
            for (int n = 0; n < 2; ++n)
                c[m][n] = (f32x4){0.f, 0.f, 0.f, 0.f};

        #pragma unroll
        for (int ks = 0; ks < 4; ++ks) {   // K = 128 = 4 * 32
            int slot = ks * 4 + lg;
            bf16x8 a[4], b[2];
            #pragma unroll
            for (int m = 0; m < 4; ++m) {
                int r = wr * 64 + m * 16 + lr;
                a[m] = *reinterpret_cast<const bf16x8*>(&bufA[r * 16 + (slot ^ (r & 15))]);
            }
            #pragma unroll
            for (int n = 0; n < 2; ++n) {
                int r = wc * 32 + n * 16 + lr;
                // B rows are elements 128..255: swizzle uses (128+r)&15 == r&15
                b[n] = *reinterpret_cast<const bf16x8*>(&bufB[r * 16 + (slot ^ (r & 15))]);
            }
            #pragma unroll
            for (int m = 0; m < 4; ++m)
                #pragma unroll
                for (int n = 0; n < 2; ++n)
                    c[m][n] = __builtin_amdgcn_mfma_f32_16x16x32_bf16(a[m], b[n], c[m][n], 0, 0, 0);
        }

        // ---- epilogue: Schraudolph fast-exp, per-thread running sums ----
        f32x2 p2 = (f32x2){0.f, 0.f};
        if (cti != ctj) {
            #pragma unroll
            for (int m = 0; m < 4; ++m)
                #pragma unroll
                for (int n = 0; n < 2; ++n) {
                    f32x4 g = c[m][n];
                    f32x2 u0 = (f32x2){g[0], g[1]} * K1 + K0;   // v_pk_fma_f32
                    f32x2 u1 = (f32x2){g[2], g[3]} * K1 + K0;
                    p2 += (f32x2){__int_as_float((int)u0.x),
                                  __int_as_float((int)u0.y)};
                    p2 += (f32x2){__int_as_float((int)u1.x),
                                  __int_as_float((int)u1.y)};
                }
        } else {
            // diagonal tile: strict upper only; clamp at w=0 (g_ii ~ 1)
            int crow0 = wr * 64 + lg * 4;  // C layout: row=(lane>>4)*4+reg
            int ccol0 = wc * 32 + lr;      //           col=lane&15
            float ps = 0.0f;
            #pragma unroll
            for (int m = 0; m < 4; ++m)
                #pragma unroll
                for (int n = 0; n < 2; ++n)
                    #pragma unroll
                    for (int r = 0; r < 4; ++r) {
                        float uu = fminf(fmaf(c[m][n][r], K1, K0), B);
                        float e = __int_as_float((int)uu);
                        int lrow = crow0 + m * 16 + r;
                        int lcol = ccol0 + n * 16;
                        ps += (lcol > lrow) ? e : 0.0f;
                    }
            p2.x = ps;
        }
        if (cmat) ak2 += p2; else aq2 += p2;

        __syncthreads();                   // drains staged loads (aged through
                                           // compute) + protects buf reuse
        cur ^= 1;
        t = tn;
        cmat = nmat; cti = nti; ctj = ntj;
    }

    // ---- one reduce per block ----
    float pq = aq2.x + aq2.y, pk = ak2.x + ak2.y;
    #pragma unroll
    for (int off = 32; off; off >>= 1) {
        pq += __shfl_xor(pq, off);
        pk += __shfl_xor(pk, off);
    }
    if (lane == 0) { redq[wid] = pq; redk[wid] = pk; }
    __syncthreads();
    if (tid == 0) {
        float sq = 0.0f, sk = 0.0f;
        #pragma unroll
        for (int w = 0; w < 8; ++w) { sq += redq[w]; sk += redk[w]; }
        unif_q[blockIdx.x] = sq;
        unif_k[blockIdx.x] = sk;
    }
}

// Single block: sum all partials in double, emit final scalar.
__global__ __launch_bounds__(256) void finalize(
        const float* __restrict__ align_part,   // [2048]
        const float* __restrict__ unif_q,       // [GRID]
        const float* __restrict__ unif_k,       // [GRID]
        float* __restrict__ out) {
    int tid = threadIdx.x;
    double a = 0.0, qs = 0.0, ks = 0.0;
    for (int i = tid; i < 2048; i += 256) a += (double)align_part[i];
    if (tid < GRID) { qs = (double)unif_q[tid]; ks = (double)unif_k[tid]; }

    __shared__ double sa[256], sq[256], sk[256];
    sa[tid] = a; sq[tid] = qs; sk[tid] = ks;
    __syncthreads();
    for (int s = 128; s; s >>= 1) {
        if (tid < s) {
            sa[tid] += sa[tid + s];
            sq[tid] += sq[tid + s];
            sk[tid] += sk[tid + s];
        }
        __syncthreads();
    }
    if (tid == 0) {
        const double npairs = (double)NROWS * (NROWS - 1) / 2.0;
        double align = sa[0] / (double)NROWS;
        double lq = log(sq[0] / npairs);
        double lk = log(sk[0] / npairs);
        out[0] = (float)(align + 0.5 * (lq + lk));   // LAMDA = 1
    }
}

extern "C" void kernel_launch(void* const* d_in, const int* in_sizes, int n_in,
                              void* d_out, int out_size, void* d_ws, size_t ws_size,
                              hipStream_t stream) {
    const float* q = (const float*)d_in[0];
    const float* k = (const float*)d_in[1];
    char* ws = (char*)d_ws;
    unsigned int* qn = (unsigned int*)ws;                          // 2 MiB bf16
    unsigned int* kn = (unsigned int*)(ws + (size_t)2 * 1024 * 1024);
    float* align_part = (float*)(ws + (size_t)4 * 1024 * 1024);            // 2048 f32
    float* unif_q = (float*)(ws + (size_t)4 * 1024 * 1024 + 16384);        // GRID f32
    float* unif_k = (float*)(ws + (size_t)4 * 1024 * 1024 + 32768);        // GRID f32
    float* out = (float*)d_out;

    norm_kernel<<<NROWS / 4, 256, 0, stream>>>(q, k, qn, kn, align_part);
    gram_kernel<<<GRID, 512, 0, stream>>>((const uint4*)qn, (const uint4*)kn, unif_q, unif_k);
    finalize<<<1, 256, 0, stream>>>(align_part, unif_q, unif_k, out);
}